// Round 18
// baseline (137.027 us; speedup 1.0000x reference)
//
#include <hip/hip_runtime.h>
#include <hip/hip_bf16.h>

#define B_ 32
#define H_ 768
#define K_ 65536
#define TOPK 25
#define ENDK 25
#define WLO 28672            // window start bin: values in [-0.0625, 0.0625)
#define NWB 8192             // window bins (16 sigma of the cos distribution)

// ws byte offsets
#define OFF_LQT  0           // bf16 A-frags, per-lane fragment order: 48 KB
#define OFF_X1   98304
#define OFF_X2   196608
#define OFF_CNT  294912      // u32: [2..33]=poscnt[b]
#define OFF_HIST 524288      // u32[64*8192] = 2 MB  (suffix-CDF S)
#define OFF_BIDX 8388608     // u16[32*65536] = 4 MB window-relative bin indices

typedef __attribute__((ext_vector_type(8))) short short8v;
typedef __attribute__((ext_vector_type(4))) float f32x4;

__device__ inline short f2bf(float f) {
    unsigned u = __builtin_bit_cast(unsigned, f);
    unsigned r = (u + 0x7FFFu + ((u >> 16) & 1u)) >> 16;   // RNE
    return (short)r;
}

// x_out[b][j] = (tanh?) ( sum_e in[b][e]*w[j][e] + bias[j] ); 4 waves/block
__global__ __launch_bounds__(256) void k_dense(const float* __restrict__ in, const float* __restrict__ w,
                        const float* __restrict__ bias, float* __restrict__ out,
                        int apply_tanh) {
    int j = blockIdx.x * 4 + (threadIdx.x >> 6);
    int lane = threadIdx.x & 63;
    float acc[B_];
#pragma unroll
    for (int b = 0; b < B_; ++b) acc[b] = 0.f;
#pragma unroll
    for (int c = 0; c < 12; ++c) {
        float wv = w[j * H_ + lane + 64 * c];
#pragma unroll
        for (int b = 0; b < B_; ++b) acc[b] += in[b * H_ + lane + 64 * c] * wv;
    }
    float bj = bias[j];
#pragma unroll
    for (int b = 0; b < B_; ++b) {
        float v = acc[b];
#pragma unroll
        for (int off = 32; off > 0; off >>= 1) v += __shfl_xor(v, off, 64);
        if (lane == b) {
            float r = v + bj;
            out[b * H_ + j] = apply_tanh ? tanhf(r) : r;
        }
    }
}

// Normalize rows of x2; emit bf16 A-fragments in per-lane order.
__global__ void k_norm(const float* __restrict__ x2, short* __restrict__ lqt) {
    int b = blockIdx.x, lane = threadIdx.x;
    float v[12];
    float ss = 0.f;
#pragma unroll
    for (int c = 0; c < 12; ++c) {
        v[c] = x2[b * H_ + lane + 64 * c];
        ss += v[c] * v[c];
    }
#pragma unroll
    for (int off = 32; off > 0; off >>= 1) ss += __shfl_xor(ss, off, 64);
    float rn = 1.0f / sqrtf(ss);
    int frag = b >> 4, br = b & 15;
#pragma unroll
    for (int c = 0; c < 12; ++c) {
        int k = lane + 64 * c;
        int ch = k >> 5, kk = k & 31;
        int idx = ((ch * 2 + frag) << 9) + ((((kk >> 3) << 4) | br) << 3) + (kk & 7);
        lqt[idx] = f2bf(v[c] * rn);
    }
}

// MFMA GEMM (32 x 65536 x 768) -> u16 window-relative bin indices (clamped).
// H-split across wave pairs, 4-deep chunk prefetch, combine via LDS.
// fq loads are NON-TEMPORAL (zero reuse; keeps output dirty-resident in L3).
__global__ __launch_bounds__(256) void k_gemm_bin(
    const float* __restrict__ fq, const short* __restrict__ lqt,
    unsigned short* __restrict__ binidx) {
    __shared__ float xch[2][64][8];
    const int l = threadIdx.x & 63;
    const int w = threadIdx.x >> 6;       // 0..3
    const int pair = w >> 1;              // 0..1 : which 16-row fq tile
    const int half = w & 1;               // 0..1 : which H half
    const int nb = (blockIdx.x * 2 + pair) * 16;
    const int r = l & 15, o = l >> 4;

    const float* fbase = fq + (size_t)(nb + r) * H_ + half * 384 + o * 8;
    const short* abase = lqt + (half * 12) * 1024 + l * 8;

    f32x4 acc0 = {0.f, 0.f, 0.f, 0.f};
    f32x4 acc1 = {0.f, 0.f, 0.f, 0.f};

    f32x4 pa[4], pb[4];
#pragma unroll
    for (int p = 0; p < 4; ++p) {
        pa[p] = __builtin_nontemporal_load((const f32x4*)(fbase + p * 32));
        pb[p] = __builtin_nontemporal_load((const f32x4*)(fbase + p * 32 + 4));
    }
#pragma unroll
    for (int ch = 0; ch < 12; ++ch) {
        f32x4 b0 = pa[ch & 3];
        f32x4 b1 = pb[ch & 3];
        if (ch + 4 < 12) {
            pa[ch & 3] = __builtin_nontemporal_load((const f32x4*)(fbase + (ch + 4) * 32));
            pb[ch & 3] = __builtin_nontemporal_load((const f32x4*)(fbase + (ch + 4) * 32 + 4));
        }
        short8v bf;
        bf[0] = f2bf(b0[0]); bf[1] = f2bf(b0[1]); bf[2] = f2bf(b0[2]); bf[3] = f2bf(b0[3]);
        bf[4] = f2bf(b1[0]); bf[5] = f2bf(b1[1]); bf[6] = f2bf(b1[2]); bf[7] = f2bf(b1[3]);
        short8v a0 = *(const short8v*)(abase + ch * 1024);
        short8v a1 = *(const short8v*)(abase + ch * 1024 + 512);
        acc0 = __builtin_amdgcn_mfma_f32_16x16x32_bf16(a0, bf, acc0, 0, 0, 0);
        acc1 = __builtin_amdgcn_mfma_f32_16x16x32_bf16(a1, bf, acc1, 0, 0, 0);
    }

    if (half == 1) {
#pragma unroll
        for (int i = 0; i < 4; ++i) {
            xch[pair][l][i] = acc0[i];
            xch[pair][l][i + 4] = acc1[i];
        }
    }
    __syncthreads();
    if (half == 0) {
        const int myk = nb + r;
#pragma unroll
        for (int i = 0; i < 4; ++i) {
            acc0[i] += xch[pair][l][i];
            acc1[i] += xch[pair][l][i + 4];
        }
        // D layout: col = lane&15 (fq row k), row m = (lane>>4)*4 + reg (b)
#define EMIT(ACC, MT) \
        _Pragma("unroll") \
        for (int i = 0; i < 4; ++i) { \
            int m = (MT) * 16 + o * 4 + i; \
            float v = ACC[i]; \
            int bin = (int)floorf((v + 0.5f) * 65536.0f) - WLO; \
            bin = bin < 0 ? 0 : (bin > NWB - 1 ? NWB - 1 : bin); \
            binidx[(size_t)m * K_ + myk] = (unsigned short)bin; \
        }
        EMIT(acc0, 0)
        EMIT(acc1, 1)
#undef EMIT
    }
}

// Fused histogram + suffix-CDF scan. 64 blocks = (b, g). Each block
// accumulates only its g-group into one 32 KB LDS window over row b's full
// binidx, then scans the window in-LDS and writes its S segment directly.
// poscnt[b] = g=1 block's match count (single writer, no atomics).
__global__ __launch_bounds__(1024) void k_histscan(
    const unsigned short* __restrict__ binidx,
    const int* __restrict__ labels, const int* __restrict__ lblq,
    unsigned* __restrict__ S, unsigned* __restrict__ poscnt) {
    __shared__ unsigned lh[NWB];
    __shared__ unsigned wred[16];
    __shared__ unsigned wsum[16];
    const int b = blockIdx.x >> 1, g = blockIdx.x & 1, t = threadIdx.x;
    for (int j = t; j < NWB; j += 1024) lh[j] = 0u;
    __syncthreads();
    const int mylab = labels[b];
    const unsigned* row32 = (const unsigned*)(binidx + (size_t)b * K_);
    const int2* lb2 = (const int2*)lblq;
    unsigned gsum = 0;
#pragma unroll 4
    for (int i = 0; i < 32; ++i) {
        int j = i * 1024 + t;
        unsigned v = row32[j];
        int2 lb = lb2[j];
        int g0 = (lb.x == mylab) ? 1 : 0;
        int g1 = (lb.y == mylab) ? 1 : 0;
        gsum += (unsigned)(g0 + g1);
        if (g0 == g) atomicAdd(&lh[v & 0xFFFFu], 1u);
        if (g1 == g) atomicAdd(&lh[v >> 16], 1u);
    }
    // block-reduce gsum (match count); g=1 block stores poscnt[b]
#pragma unroll
    for (int off = 32; off > 0; off >>= 1) gsum += (unsigned)__shfl_xor((int)gsum, off, 64);
    if ((t & 63) == 0) wred[t >> 6] = gsum;
    __syncthreads();      // also orders lh atomics before the scan below
    if (t == 0 && g == 1) {
        unsigned s = 0;
#pragma unroll
        for (int i = 0; i < 16; ++i) s += wred[i];
        poscnt[b] = s;
    }
    // in-LDS suffix-CDF scan of the 8192-bin window
    int lane = t & 63, wid = t >> 6;
    unsigned cnt[8];
    unsigned s = 0;
#pragma unroll
    for (int i = 0; i < 8; ++i) {
        cnt[i] = lh[t * 8 + i];
        s += cnt[i];
    }
    unsigned vv = s;
#pragma unroll
    for (int off = 1; off < 64; off <<= 1) {
        unsigned u = (unsigned)__shfl_up((int)vv, off, 64);
        if (lane >= off) vv += u;
    }
    if (lane == 63) wsum[wid] = vv;
    __syncthreads();
    unsigned wexcl = 0, tot = 0;
#pragma unroll
    for (int i = 0; i < 16; ++i) {
        unsigned x = wsum[i];
        if (i < wid) wexcl += x;
        tot += x;
    }
    unsigned run = wexcl + vv - s;   // elements in bins below mine
    unsigned* h = S + (size_t)blockIdx.x * NWB + t * 8;
#pragma unroll
    for (int i = 0; i < 8; ++i) {
        unsigned c = cnt[i];
        h[i] = tot - run;            // S[bin]
        run += c;
    }
}

// rank p (descending) -> window bin: largest i with S[i] > p  (full search)
__device__ inline int bsearch_bin(const unsigned* __restrict__ S, unsigned p) {
    int lo = 0, hi = NWB;
#pragma unroll
    for (int it = 0; it < 13; ++it) {
        if (hi - lo > 1) {
            int mid = (lo + hi) >> 1;
            bool gt = S[mid] > p;
            lo = gt ? mid : lo;
            hi = gt ? hi : mid;
        }
    }
    return lo;
}

// narrowed search: answer known to lie in [lo, hi], S[lo] > p guaranteed
__device__ inline int bsearch_range(const unsigned* __restrict__ S, unsigned p,
                                    int lo, int hi) {
    ++hi;                           // half-open
    while (hi - lo > 1) {
        int mid = (lo + hi) >> 1;
        if (S[mid] > p) lo = mid; else hi = mid;
    }
    return lo;
}

__device__ inline float bin_val(int wbin) {
    return ((float)(wbin + WLO) + 0.5f) * (1.0f / 65536.0f) - 0.5f;
}

// Output writer. Block-contiguous ranks -> 2 boundary searches bound all
// threads' bins; per-thread narrowed search on the L2-hot window.
// pos_min computed inline from poscnt (32 loads, trivial).
__global__ __launch_bounds__(1024) void k_out(const unsigned* __restrict__ S,
                                              const unsigned* __restrict__ poscnt,
                                              float* __restrict__ out, int W) {
    int b = blockIdx.x;       // 0..31
    int cb = blockIdx.y;
    const float invT = 14.285714285714286f;  // 1/0.07
    __shared__ int bnd[2];    // [0]=lo bin, [1]=hi bin for this block's ranks
    const unsigned* Sn = S + (size_t)(b * 2) * NWB;

    int r0 = cb * 1024;                       // lowest rank in block
    int r1 = min(r0 + 1023, W - 2);           // highest rank in block
    if (threadIdx.x == 0) bnd[1] = bsearch_bin(Sn, (unsigned)r0);  // high bin
    if (threadIdx.x == 1) bnd[0] = bsearch_bin(Sn, (unsigned)r1);  // low bin

    if (cb == 0 && threadIdx.x >= 64 && threadIdx.x < 64 + TOPK + ENDK) {
        unsigned pmv = 0xffffffffu;
#pragma unroll
        for (int i = 0; i < B_; ++i) pmv = min(pmv, poscnt[i]);
        int pm = (int)pmv;
        int j = threadIdx.x - 64;
        int p = (j < TOPK) ? j : (pm - ENDK + (j - TOPK));
        const unsigned* Sp = S + (size_t)(b * 2 + 1) * NWB;
        int bin = bsearch_bin(Sp, (unsigned)p);
        out[(size_t)(b * (TOPK + ENDK) + j) * W] = bin_val(bin) * invT;
    }
    __syncthreads();

    int c = 1 + cb * 1024 + threadIdx.x;
    if (c < W) {
        int bin = bsearch_range(Sn, (unsigned)(c - 1), bnd[0], bnd[1]);
        float v = bin_val(bin) * invT;
        float* o = out + (size_t)b * (TOPK + ENDK) * W + c;
#pragma unroll
        for (int r = 0; r < TOPK + ENDK; ++r) o[(size_t)r * W] = v;
    }
}

extern "C" void kernel_launch(void* const* d_in, const int* in_sizes, int n_in,
                              void* d_out, int out_size, void* d_ws, size_t ws_size,
                              hipStream_t stream) {
    const float* q   = (const float*)d_in[0];
    const float* dw  = (const float*)d_in[1];
    const float* db  = (const float*)d_in[2];
    const float* ow  = (const float*)d_in[3];
    const float* ob  = (const float*)d_in[4];
    const int* labels = (const int*)d_in[5];
    const int* lblq   = (const int*)d_in[6];
    const float* fq   = (const float*)d_in[7];

    char* ws = (char*)d_ws;
    short* lqt = (short*)(ws + OFF_LQT);
    float* x1 = (float*)(ws + OFF_X1);
    float* x2 = (float*)(ws + OFF_X2);
    unsigned* cnt  = (unsigned*)(ws + OFF_CNT);
    unsigned* S    = (unsigned*)(ws + OFF_HIST);
    unsigned short* binidx = (unsigned short*)(ws + OFF_BIDX);

    int W = out_size / (B_ * (TOPK + ENDK));  // 1 + neg_min

    k_dense<<<H_ / 4, 256, 0, stream>>>(q, dw, db, x1, 1);
    k_dense<<<H_ / 4, 256, 0, stream>>>(x1, ow, ob, x2, 0);
    k_norm<<<B_, 64, 0, stream>>>(x2, lqt);
    k_gemm_bin<<<K_ / 32, 256, 0, stream>>>(fq, lqt, binidx);
    k_histscan<<<B_ * 2, 1024, 0, stream>>>(binidx, labels, lblq, S, cnt + 2);

    dim3 gb(B_, (unsigned)((W - 1 + 1023) / 1024));
    k_out<<<gb, 1024, 0, stream>>>(S, cnt + 2, (float*)d_out, W);
}

// Round 19
// 132.667 us; speedup vs baseline: 1.0329x; 1.0329x over previous
//
#include <hip/hip_runtime.h>
#include <hip/hip_bf16.h>

#define B_ 32
#define H_ 768
#define K_ 65536
#define TOPK 25
#define ENDK 25
#define WLO 28672            // window start bin: values in [-0.0625, 0.0625)
#define NWB 8192             // window bins (16 sigma of the cos distribution)

// ws byte offsets
#define OFF_LQT  0           // bf16 A-frags, per-lane fragment order: 48 KB
#define OFF_X1   98304
#define OFF_X2   196608
#define OFF_CNT  294912      // u32: [1]=pos_min, [2..33]=poscnt[b]
#define OFF_HIST 524288      // u32[64*8192] = 2 MB  (suffix-CDF S)
#define OFF_SUBH 4194304     // u32[64*2*8192] = 4 MB per-(b,half) window hists
#define OFF_BIDX 8388608     // u16[32*65536] = 4 MB window-relative bin indices

typedef __attribute__((ext_vector_type(8))) short short8v;
typedef __attribute__((ext_vector_type(4))) float f32x4;

__device__ inline short f2bf(float f) {
    unsigned u = __builtin_bit_cast(unsigned, f);
    unsigned r = (u + 0x7FFFu + ((u >> 16) & 1u)) >> 16;   // RNE
    return (short)r;
}

// x_out[b][j] = (tanh?) ( sum_e in[b][e]*w[j][e] + bias[j] ); 4 waves/block
__global__ __launch_bounds__(256) void k_dense(const float* __restrict__ in, const float* __restrict__ w,
                        const float* __restrict__ bias, float* __restrict__ out,
                        int apply_tanh) {
    int j = blockIdx.x * 4 + (threadIdx.x >> 6);
    int lane = threadIdx.x & 63;
    float acc[B_];
#pragma unroll
    for (int b = 0; b < B_; ++b) acc[b] = 0.f;
#pragma unroll
    for (int c = 0; c < 12; ++c) {
        float wv = w[j * H_ + lane + 64 * c];
#pragma unroll
        for (int b = 0; b < B_; ++b) acc[b] += in[b * H_ + lane + 64 * c] * wv;
    }
    float bj = bias[j];
#pragma unroll
    for (int b = 0; b < B_; ++b) {
        float v = acc[b];
#pragma unroll
        for (int off = 32; off > 0; off >>= 1) v += __shfl_xor(v, off, 64);
        if (lane == b) {
            float r = v + bj;
            out[b * H_ + j] = apply_tanh ? tanhf(r) : r;
        }
    }
}

// Normalize rows of x2; emit bf16 A-fragments in per-lane order.
// Also zeroes poscnt[b] (accumulated by k_hist via atomicAdd).
__global__ void k_norm(const float* __restrict__ x2, short* __restrict__ lqt,
                       unsigned* __restrict__ poscnt) {
    int b = blockIdx.x, lane = threadIdx.x;
    if (lane == 0) poscnt[b] = 0u;
    float v[12];
    float ss = 0.f;
#pragma unroll
    for (int c = 0; c < 12; ++c) {
        v[c] = x2[b * H_ + lane + 64 * c];
        ss += v[c] * v[c];
    }
#pragma unroll
    for (int off = 32; off > 0; off >>= 1) ss += __shfl_xor(ss, off, 64);
    float rn = 1.0f / sqrtf(ss);
    int frag = b >> 4, br = b & 15;
#pragma unroll
    for (int c = 0; c < 12; ++c) {
        int k = lane + 64 * c;
        int ch = k >> 5, kk = k & 31;
        int idx = ((ch * 2 + frag) << 9) + ((((kk >> 3) << 4) | br) << 3) + (kk & 7);
        lqt[idx] = f2bf(v[c] * rn);
    }
}

// MFMA GEMM (32 x 65536 x 768) -> u16 window-relative bin indices (clamped).
// H-split across wave pairs, 4-deep chunk prefetch, combine via LDS.
// fq loads are NON-TEMPORAL (zero reuse; keeps output dirty-resident in L3).
__global__ __launch_bounds__(256) void k_gemm_bin(
    const float* __restrict__ fq, const short* __restrict__ lqt,
    unsigned short* __restrict__ binidx) {
    __shared__ float xch[2][64][8];
    const int l = threadIdx.x & 63;
    const int w = threadIdx.x >> 6;       // 0..3
    const int pair = w >> 1;              // 0..1 : which 16-row fq tile
    const int half = w & 1;               // 0..1 : which H half
    const int nb = (blockIdx.x * 2 + pair) * 16;
    const int r = l & 15, o = l >> 4;

    const float* fbase = fq + (size_t)(nb + r) * H_ + half * 384 + o * 8;
    const short* abase = lqt + (half * 12) * 1024 + l * 8;

    f32x4 acc0 = {0.f, 0.f, 0.f, 0.f};
    f32x4 acc1 = {0.f, 0.f, 0.f, 0.f};

    f32x4 pa[4], pb[4];
#pragma unroll
    for (int p = 0; p < 4; ++p) {
        pa[p] = __builtin_nontemporal_load((const f32x4*)(fbase + p * 32));
        pb[p] = __builtin_nontemporal_load((const f32x4*)(fbase + p * 32 + 4));
    }
#pragma unroll
    for (int ch = 0; ch < 12; ++ch) {
        f32x4 b0 = pa[ch & 3];
        f32x4 b1 = pb[ch & 3];
        if (ch + 4 < 12) {
            pa[ch & 3] = __builtin_nontemporal_load((const f32x4*)(fbase + (ch + 4) * 32));
            pb[ch & 3] = __builtin_nontemporal_load((const f32x4*)(fbase + (ch + 4) * 32 + 4));
        }
        short8v bf;
        bf[0] = f2bf(b0[0]); bf[1] = f2bf(b0[1]); bf[2] = f2bf(b0[2]); bf[3] = f2bf(b0[3]);
        bf[4] = f2bf(b1[0]); bf[5] = f2bf(b1[1]); bf[6] = f2bf(b1[2]); bf[7] = f2bf(b1[3]);
        short8v a0 = *(const short8v*)(abase + ch * 1024);
        short8v a1 = *(const short8v*)(abase + ch * 1024 + 512);
        acc0 = __builtin_amdgcn_mfma_f32_16x16x32_bf16(a0, bf, acc0, 0, 0, 0);
        acc1 = __builtin_amdgcn_mfma_f32_16x16x32_bf16(a1, bf, acc1, 0, 0, 0);
    }

    if (half == 1) {
#pragma unroll
        for (int i = 0; i < 4; ++i) {
            xch[pair][l][i] = acc0[i];
            xch[pair][l][i + 4] = acc1[i];
        }
    }
    __syncthreads();
    if (half == 0) {
        const int myk = nb + r;
#pragma unroll
        for (int i = 0; i < 4; ++i) {
            acc0[i] += xch[pair][l][i];
            acc1[i] += xch[pair][l][i + 4];
        }
        // D layout: col = lane&15 (fq row k), row m = (lane>>4)*4 + reg (b)
#define EMIT(ACC, MT) \
        _Pragma("unroll") \
        for (int i = 0; i < 4; ++i) { \
            int m = (MT) * 16 + o * 4 + i; \
            float v = ACC[i]; \
            int bin = (int)floorf((v + 0.5f) * 65536.0f) - WLO; \
            bin = bin < 0 ? 0 : (bin > NWB - 1 ? NWB - 1 : bin); \
            binidx[(size_t)m * K_ + myk] = (unsigned short)bin; \
        }
        EMIT(acc0, 0)
        EMIT(acc1, 1)
#undef EMIT
    }
}

// Privatized window histogram. 64 blocks = (b, K-half). LDS u32[2][8192];
// paired-u16 loads (NON-TEMPORAL: binidx slice is read exactly once);
// plain-store dump to exclusive subhist slice; poscnt via one atomicAdd/block.
__global__ __launch_bounds__(1024) void k_hist(
    const unsigned short* __restrict__ binidx,
    const int* __restrict__ labels, const int* __restrict__ lblq,
    unsigned* __restrict__ subhist, unsigned* __restrict__ poscnt) {
    __shared__ unsigned lh[2 * NWB];
    __shared__ unsigned wred[16];
    const int b = blockIdx.x >> 1, half = blockIdx.x & 1, t = threadIdx.x;
    for (int j = t; j < 2 * NWB; j += 1024) lh[j] = 0u;
    __syncthreads();
    const int mylab = labels[b];
    const unsigned* row32 = (const unsigned*)(binidx + (size_t)b * K_) + half * 16384;
    const int2* lb2 = (const int2*)(lblq + half * 32768);
    unsigned gsum = 0;
#pragma unroll 4
    for (int i = 0; i < 16; ++i) {
        int j = i * 1024 + t;
        unsigned v = __builtin_nontemporal_load(&row32[j]);
        int2 lb = lb2[j];
        int g0 = (lb.x == mylab) ? 1 : 0;
        int g1 = (lb.y == mylab) ? 1 : 0;
        gsum += (unsigned)(g0 + g1);
        atomicAdd(&lh[g0 * NWB + (v & 0xFFFFu)], 1u);
        atomicAdd(&lh[g1 * NWB + (v >> 16)], 1u);
    }
#pragma unroll
    for (int off = 32; off > 0; off >>= 1) gsum += (unsigned)__shfl_xor((int)gsum, off, 64);
    if ((t & 63) == 0) wred[t >> 6] = gsum;
    __syncthreads();
    if (t == 0) {
        unsigned s = 0;
#pragma unroll
        for (int i = 0; i < 16; ++i) s += wred[i];
        atomicAdd(&poscnt[b], s);
    }
    unsigned* dst = subhist + (size_t)blockIdx.x * 2 * NWB;
    for (int j = t; j < 2 * NWB; j += 1024) dst[j] = lh[j];
}

// Fold the 2 K-half subhists -> suffix-CDF S (S[i] = # elements in bins >= i).
// Block 0 also computes pos_min from poscnt (ready by stream order).
__global__ __launch_bounds__(1024) void k_scan(const unsigned* __restrict__ subhist,
                                               unsigned* __restrict__ S,
                                               const unsigned* __restrict__ poscnt,
                                               unsigned* __restrict__ posmin) {
    int seg = blockIdx.x, b = seg >> 1, g = seg & 1;
    int t = threadIdx.x, lane = t & 63, wid = t >> 6;
    if (seg == 0 && t < 64) {
        unsigned cp = (t < B_) ? poscnt[t] : 0x7fffffffu;
#pragma unroll
        for (int off = 32; off > 0; off >>= 1) {
            unsigned o = (unsigned)__shfl_xor((int)cp, off, 64);
            cp = o < cp ? o : cp;
        }
        if (t == 0) *posmin = cp;
    }
    const unsigned* s0 = subhist + (size_t)(b * 2) * 2 * NWB + g * NWB;
    const unsigned* s1 = subhist + (size_t)(b * 2 + 1) * 2 * NWB + g * NWB;
    unsigned cnt[8];
    unsigned s = 0;
#pragma unroll
    for (int i = 0; i < 8; ++i) {
        int bin = t * 8 + i;
        cnt[i] = s0[bin] + s1[bin];
        s += cnt[i];
    }
    unsigned vv = s;
#pragma unroll
    for (int off = 1; off < 64; off <<= 1) {
        unsigned u = (unsigned)__shfl_up((int)vv, off, 64);
        if (lane >= off) vv += u;
    }
    __shared__ unsigned wsum[16];
    if (lane == 63) wsum[wid] = vv;
    __syncthreads();
    unsigned wexcl = 0, tot = 0;
#pragma unroll
    for (int i = 0; i < 16; ++i) {
        unsigned x = wsum[i];
        if (i < wid) wexcl += x;
        tot += x;
    }
    unsigned run = wexcl + vv - s;   // elements in bins below mine
    unsigned* h = S + (size_t)seg * NWB + t * 8;
#pragma unroll
    for (int i = 0; i < 8; ++i) {
        unsigned c = cnt[i];
        h[i] = tot - run;            // S[bin]
        run += c;
    }
}

// rank p (descending) -> window bin: largest i with S[i] > p
__device__ inline int bsearch_bin(const unsigned* __restrict__ S, unsigned p) {
    int lo = 0, hi = NWB;
#pragma unroll
    for (int it = 0; it < 13; ++it) {
        if (hi - lo > 1) {
            int mid = (lo + hi) >> 1;
            bool gt = S[mid] > p;
            lo = gt ? mid : lo;
            hi = gt ? hi : mid;
        }
    }
    return lo;
}

__device__ inline float bin_val(int wbin) {
    return ((float)(wbin + WLO) + 0.5f) * (1.0f / 65536.0f) - 0.5f;
}

// Output writer: rank-search the CDF, broadcast to 50 repeat rows (coalesced).
__global__ __launch_bounds__(1024) void k_out(const unsigned* __restrict__ S,
                                              const unsigned* __restrict__ posmin,
                                              float* __restrict__ out, int W) {
    int b = blockIdx.x;       // 0..31
    int cb = blockIdx.y;
    const float invT = 14.285714285714286f;  // 1/0.07
    if (cb == 0 && threadIdx.x < (TOPK + ENDK)) {
        int pm = (int)*posmin;
        int j = threadIdx.x;
        int p = (j < TOPK) ? j : (pm - ENDK + (j - TOPK));
        const unsigned* Sp = S + (size_t)(b * 2 + 1) * NWB;
        int bin = bsearch_bin(Sp, (unsigned)p);
        out[(size_t)(b * (TOPK + ENDK) + j) * W] = bin_val(bin) * invT;
    }
    int c = 1 + cb * 1024 + threadIdx.x;
    if (c < W) {
        const unsigned* Sn = S + (size_t)(b * 2) * NWB;
        int bin = bsearch_bin(Sn, (unsigned)(c - 1));
        float v = bin_val(bin) * invT;
        float* o = out + (size_t)b * (TOPK + ENDK) * W + c;
#pragma unroll
        for (int r = 0; r < TOPK + ENDK; ++r) o[(size_t)r * W] = v;
    }
}

extern "C" void kernel_launch(void* const* d_in, const int* in_sizes, int n_in,
                              void* d_out, int out_size, void* d_ws, size_t ws_size,
                              hipStream_t stream) {
    const float* q   = (const float*)d_in[0];
    const float* dw  = (const float*)d_in[1];
    const float* db  = (const float*)d_in[2];
    const float* ow  = (const float*)d_in[3];
    const float* ob  = (const float*)d_in[4];
    const int* labels = (const int*)d_in[5];
    const int* lblq   = (const int*)d_in[6];
    const float* fq   = (const float*)d_in[7];

    char* ws = (char*)d_ws;
    short* lqt = (short*)(ws + OFF_LQT);
    float* x1 = (float*)(ws + OFF_X1);
    float* x2 = (float*)(ws + OFF_X2);
    unsigned* cnt  = (unsigned*)(ws + OFF_CNT);
    unsigned* S    = (unsigned*)(ws + OFF_HIST);
    unsigned* subh = (unsigned*)(ws + OFF_SUBH);
    unsigned short* binidx = (unsigned short*)(ws + OFF_BIDX);

    int W = out_size / (B_ * (TOPK + ENDK));  // 1 + neg_min

    k_dense<<<H_ / 4, 256, 0, stream>>>(q, dw, db, x1, 1);
    k_dense<<<H_ / 4, 256, 0, stream>>>(x1, ow, ob, x2, 0);
    k_norm<<<B_, 64, 0, stream>>>(x2, lqt, cnt + 2);
    k_gemm_bin<<<K_ / 32, 256, 0, stream>>>(fq, lqt, binidx);
    k_hist<<<B_ * 2, 1024, 0, stream>>>(binidx, labels, lblq, subh, cnt + 2);
    k_scan<<<B_ * 2, 1024, 0, stream>>>(subh, S, cnt + 2, cnt + 1);

    dim3 gb(B_, (unsigned)((W - 1 + 1023) / 1024));
    k_out<<<gb, 1024, 0, stream>>>(S, cnt + 1, (float*)d_out, W);
}